// Round 22
// baseline (39.515 us; speedup 1.0000x reference)
//
#include <hip/hip_runtime.h>

typedef __attribute__((ext_vector_type(8))) _Float16 f16x8;
typedef __attribute__((ext_vector_type(4))) float f32x4;
typedef __attribute__((ext_vector_type(4))) _Float16 h4;
typedef __attribute__((ext_vector_type(2))) __fp16 hw2;
typedef __attribute__((ext_vector_type(2))) float v2f;

#define IMG 512
#define OUT_N 502
#define NPLANE 48
#define NGRP 8               // band-groups; each block does 4 bands = 64 rows
#define VP 520               // LDS pitch (fp16): 512 + 8 pad (keeps b128 align)
#define C1c 0.0001f
#define C2c 0.0004f

union H8u { hw2 p[4]; f16x8 v; };
union H4u { hw2 p[2]; h4 v; };

// scalar ssim (edge band only)
__device__ __forceinline__ float ssim_px(float mx, float my, float P, float M) {
    float A = mx*mx, B = my*my, mxy = mx*my;
    float sumsq = 0.5f*(P+M) - A - B;
    float sxy   = 0.25f*(P-M) - mxy;
    float num = (2.f*mxy + C1c) * (2.f*sxy + C2c);
    float den = (A + B + C1c) * (sumsq + C2c);
    return num * __builtin_amdgcn_rcpf(den);
}

// packed-pair ssim: v_pk_*_f32 chain, scalar rcp x2
__device__ __forceinline__ float ssim_px2(v2f mx, v2f my, v2f P, v2f M) {
    v2f A = mx*mx, B = my*my, mxy = mx*my;
    v2f sumsq = 0.5f*(P+M) - A - B;
    v2f sxy   = 0.25f*(P-M) - mxy;
    v2f num = (2.f*mxy + C1c) * (2.f*sxy + C2c);
    v2f den = (A + B + C1c) * (sumsq + C2c);
    return num.x * __builtin_amdgcn_rcpf(den.x)
         + num.y * __builtin_amdgcn_rcpf(den.y);
}

// Block = FOUR consecutive 16-row bands (grid 8x48 = 384 blocks -> all
// co-resident, single dispatch round). Per band: V = Data(16x32)xBand(32x16)
// banded matmul -> packed ds_write_b64; barrier; [issue next band's 64 loads,
// pinned by sched_barrier(0)]; H = Vdata(16x32)xBand(32x16) + packed-f32
// epilogue; barrier. Cross-band prefetch hides V-load latency under H-compute;
// startup (w row-sum, band_f) amortized x4; halo rows reuse L1/L2.
__global__ __launch_bounds__(512, 2) void ssim_band(
    const float* __restrict__ in, const float* __restrict__ tgt,
    const float* __restrict__ w, float* __restrict__ partial)
{
    __shared__ __attribute__((aligned(16))) _Float16 vlds[4][16][VP];
    __shared__ float g1s[16];
    __shared__ float red[8];

    const int tid   = threadIdx.x;
    const int lane  = tid & 63;
    const int wv    = tid >> 6;          // wave id 0..7
    const int bg    = blockIdx.x;        // band group: bands 4bg..4bg+3
    const int plane = blockIdx.y;
    const float* __restrict__ ip = in  + (size_t)plane * (IMG*IMG);
    const float* __restrict__ tp = tgt + (size_t)plane * (IMG*IMG);

    const int fi = lane & 15;            // A-row / B-col / D-col index
    const int kg = lane >> 4;            // k-group (0..3)
    const int kB = kg * 8;               // k base for this lane

    int idx[8];
#define SETIDX(B) \
    { const int r0b_ = (bg*4 + (B)) * 16; \
      _Pragma("unroll") \
      for (int q = 0; q < 8; ++q) { \
          const int rr = min(r0b_ + kB + q, IMG - 1); \
          idx[q] = rr * IMG + wv * 64 + fi; \
      } }

    float x0[8], y0[8], x1[8], y1[8], x2[8], y2[8], x3[8], y3[8];
#define VLOAD(T, XS, YS) \
    { _Pragma("unroll") \
      for (int q = 0; q < 8; ++q) { \
          XS[q] = ip[idx[q] + 16*(T)]; \
          YS[q] = tp[idx[q] + 16*(T)]; \
      } }
#define VLOADALL() \
    VLOAD(0, x0, y0) VLOAD(1, x1, y1) VLOAD(2, x2, y2) VLOAD(3, x3, y3) \
    __builtin_amdgcn_sched_barrier(0);   /* pin loads here (no sinking) */

    // Band-0 loads issued first: they land under the w-processing sync.
    SETIDX(0)
    VLOADALL()

    // 1D factor = row sums of the 2D kernel (exact: w2d = outer(g,g), sum = 1)
    if (tid < 11) {
        float s = 0.f;
        #pragma unroll
        for (int j = 0; j < 11; ++j) s += w[tid*11 + j];
        g1s[tid] = s;
    }
    __syncthreads();
    float g[11];
    #pragma unroll
    for (int j = 0; j < 11; ++j)
        g[j] = __int_as_float(__builtin_amdgcn_readfirstlane(__float_as_int(g1s[j])));

    // Banded weight fragment: band_f[q] = g[kB+q - fi] (zero outside 0..10).
    f16x8 band_f;
    #pragma unroll
    for (int q = 0; q < 8; ++q) {
        float wq = 0.f;
        #pragma unroll
        for (int j = 0; j <= 10; ++j)
            wq = (kB + q - fi == j) ? g[j] : wq;
        band_f[q] = (_Float16)wq;
    }

    float acc = 0.f;
    const f32x4 z = {0.f, 0.f, 0.f, 0.f};

#define VSTORE(F, D) \
    { H4u u_; \
      u_.p[0] = __builtin_amdgcn_cvt_pkrtz((D)[0], (D)[1]); \
      u_.p[1] = __builtin_amdgcn_cvt_pkrtz((D)[2], (D)[3]); \
      *reinterpret_cast<h4*>(&vlds[F][fi][cb_]) = u_.v; }

#define VPROC(T, XS, YS) \
    { H8u ux, uy; \
      ux.p[0] = __builtin_amdgcn_cvt_pkrtz(XS[0], XS[1]); \
      ux.p[1] = __builtin_amdgcn_cvt_pkrtz(XS[2], XS[3]); \
      ux.p[2] = __builtin_amdgcn_cvt_pkrtz(XS[4], XS[5]); \
      ux.p[3] = __builtin_amdgcn_cvt_pkrtz(XS[6], XS[7]); \
      uy.p[0] = __builtin_amdgcn_cvt_pkrtz(YS[0], YS[1]); \
      uy.p[1] = __builtin_amdgcn_cvt_pkrtz(YS[2], YS[3]); \
      uy.p[2] = __builtin_amdgcn_cvt_pkrtz(YS[4], YS[5]); \
      uy.p[3] = __builtin_amdgcn_cvt_pkrtz(YS[6], YS[7]); \
      f16x8 fX = ux.v, fY = uy.v; \
      f16x8 fS = fX + fY, fD = fX - fY; \
      f16x8 fP = fS * fS, fM = fD * fD; \
      f32x4 dX = __builtin_amdgcn_mfma_f32_16x16x32_f16(fX, band_f, z, 0, 0, 0); \
      f32x4 dY = __builtin_amdgcn_mfma_f32_16x16x32_f16(fY, band_f, z, 0, 0, 0); \
      f32x4 dP = __builtin_amdgcn_mfma_f32_16x16x32_f16(fP, band_f, z, 0, 0, 0); \
      f32x4 dM = __builtin_amdgcn_mfma_f32_16x16x32_f16(fM, band_f, z, 0, 0, 0); \
      const int cb_ = (wv*4 + (T))*16 + kg*4; \
      VSTORE(0, dX) VSTORE(1, dY) VSTORE(2, dP) VSTORE(3, dM) }

#define BARRIER() \
    asm volatile("s_waitcnt lgkmcnt(0)" ::: "memory"); \
    __builtin_amdgcn_s_barrier(); \
    __builtin_amdgcn_sched_barrier(0);

    // H-phase for band B: A-frag = vlds[f][fi][c0+kB..+7] (one b128/field).
#define HPROCB(T, B) \
    { const int c0_ = (wv*4 + (T))*16; \
      const int kb_ = min(c0_ + kB, IMG - 8); \
      f16x8 aX = *reinterpret_cast<const f16x8*>(&vlds[0][fi][kb_]); \
      f16x8 aY = *reinterpret_cast<const f16x8*>(&vlds[1][fi][kb_]); \
      f16x8 aP = *reinterpret_cast<const f16x8*>(&vlds[2][fi][kb_]); \
      f16x8 aM = *reinterpret_cast<const f16x8*>(&vlds[3][fi][kb_]); \
      f32x4 dX = __builtin_amdgcn_mfma_f32_16x16x32_f16(aX, band_f, z, 0, 0, 0); \
      f32x4 dY = __builtin_amdgcn_mfma_f32_16x16x32_f16(aY, band_f, z, 0, 0, 0); \
      f32x4 dP = __builtin_amdgcn_mfma_f32_16x16x32_f16(aP, band_f, z, 0, 0, 0); \
      f32x4 dM = __builtin_amdgcn_mfma_f32_16x16x32_f16(aM, band_f, z, 0, 0, 0); \
      const int oc = c0_ + fi; \
      const int r0b_ = (bg*4 + (B)) * 16; \
      const bool edge_ = (r0b_ + 16 > OUT_N); \
      if (oc < OUT_N) { \
          if (!edge_) { \
              v2f mx0 = {dX[0], dX[1]}, my0 = {dY[0], dY[1]}; \
              v2f P0  = {dP[0], dP[1]}, M0  = {dM[0], dM[1]}; \
              v2f mx1 = {dX[2], dX[3]}, my1 = {dY[2], dY[3]}; \
              v2f P1  = {dP[2], dP[3]}, M1  = {dM[2], dM[3]}; \
              acc += ssim_px2(mx0, my0, P0, M0); \
              acc += ssim_px2(mx1, my1, P1, M1); \
          } else { \
              _Pragma("unroll") \
              for (int m = 0; m < 4; ++m) { \
                  const int oy = r0b_ + kg*4 + m; \
                  if (oy < OUT_N) \
                      acc += ssim_px(dX[m], dY[m], dP[m], dM[m]); \
              } \
          } } }

    // Band step: V(b) -> barrier -> [prefetch b+1, pinned] -> H(b) -> barrier
#define BANDSTEP(B, LAST) \
    VPROC(0, x0, y0) VPROC(1, x1, y1) VPROC(2, x2, y2) VPROC(3, x3, y3) \
    BARRIER() \
    if (!(LAST)) { SETIDX((B)+1) VLOADALL() } \
    HPROCB(0, B) HPROCB(1, B) HPROCB(2, B) HPROCB(3, B) \
    if (!(LAST)) { BARRIER() }

    BANDSTEP(0, 0)
    BANDSTEP(1, 0)
    BANDSTEP(2, 0)
    BANDSTEP(3, 1)

    // block reduction: wave shuffle, then 8 wave-partials through LDS
    #pragma unroll
    for (int off = 32; off > 0; off >>= 1)
        acc += __shfl_down(acc, off, 64);
    if (lane == 0) red[wv] = acc;
    __syncthreads();
    if (tid == 0) {
        float t = 0.f;
        #pragma unroll
        for (int i = 0; i < 8; ++i) t += red[i];
        partial[plane * NGRP + bg] = t;
    }
}

// Deterministic final reduction: fixed traversal, double accumulation.
__global__ __launch_bounds__(256) void ssim_final(
    const float* __restrict__ partial, int n, float* __restrict__ out)
{
    __shared__ double red[256];
    double s = 0.0;
    for (int i = threadIdx.x; i < n; i += 256) s += (double)partial[i];
    red[threadIdx.x] = s;
    __syncthreads();
    for (int off = 128; off > 0; off >>= 1) {
        if (threadIdx.x < off) red[threadIdx.x] += red[threadIdx.x + off];
        __syncthreads();
    }
    if (threadIdx.x == 0) out[0] = (float)(1.0 - red[0] / (double)NPLANE);
}

extern "C" void kernel_launch(void* const* d_in, const int* in_sizes, int n_in,
                              void* d_out, int out_size, void* d_ws, size_t ws_size,
                              hipStream_t stream) {
    const float* in  = (const float*)d_in[0];
    const float* tgt = (const float*)d_in[1];
    const float* wt  = (const float*)d_in[2];
    float* out  = (float*)d_out;
    float* part = (float*)d_ws;

    dim3 grid(NGRP, NPLANE);     // 8 band-groups x 48 planes = 384 blocks
    ssim_band<<<grid, 512, 0, stream>>>(in, tgt, wt, part);
    ssim_final<<<1, 256, 0, stream>>>(part, NGRP * NPLANE, out);
}

// Round 23
// 30.960 us; speedup vs baseline: 1.2763x; 1.2763x over previous
//
#include <hip/hip_runtime.h>

typedef __attribute__((ext_vector_type(8))) _Float16 f16x8;
typedef __attribute__((ext_vector_type(4))) float f32x4;
typedef __attribute__((ext_vector_type(4))) _Float16 h4;
typedef __attribute__((ext_vector_type(2))) __fp16 hw2;
typedef __attribute__((ext_vector_type(2))) float v2f;

#define IMG 512
#define OUT_N 502
#define NPLANE 48
#define NBAND 32             // 16 output rows per band
#define NBLK (NBAND * NPLANE)
#define VP 520               // LDS pitch (fp16): 512 + 8 pad (keeps b128 align)
#define C1c 0.0001f
#define C2c 0.0004f

union H8u { hw2 p[4]; f16x8 v; };
union H4u { hw2 p[2]; h4 v; };

// scalar ssim (edge band only)
__device__ __forceinline__ float ssim_px(float mx, float my, float P, float M) {
    float A = mx*mx, B = my*my, mxy = mx*my;
    float sumsq = 0.5f*(P+M) - A - B;
    float sxy   = 0.25f*(P-M) - mxy;
    float num = (2.f*mxy + C1c) * (2.f*sxy + C2c);
    float den = (A + B + C1c) * (sumsq + C2c);
    return num * __builtin_amdgcn_rcpf(den);
}

// packed-pair ssim: v_pk_*_f32 chain, scalar rcp x2
__device__ __forceinline__ float ssim_px2(v2f mx, v2f my, v2f P, v2f M) {
    v2f A = mx*mx, B = my*my, mxy = mx*my;
    v2f sumsq = 0.5f*(P+M) - A - B;
    v2f sxy   = 0.25f*(P-M) - mxy;
    v2f num = (2.f*mxy + C1c) * (2.f*sxy + C2c);
    v2f den = (A + B + C1c) * (sumsq + C2c);
    return num.x * __builtin_amdgcn_rcpf(den.x)
         + num.y * __builtin_amdgcn_rcpf(den.y);
}

// Block = one 16-row output band, 512 threads (8 waves). Both blurs are banded
// matmuls on the matrix pipe (layouts verified absmax 0.0 in R19):
//   V: D = Data(16x32) x Band(32x16) -> lane holds out-row fi, 4 consecutive
//      cols -> one packed ds_write_b64 per field.
//   H: D = Vdata(16x32) x Band(32x16), A-frag = one ds_read_b128 per field.
// R23 deltas vs R20 (best, 39.4us):
//  - bijective XCD swizzle: flat block id f -> s=(f&7)*192+(f>>3); each XCD
//    owns 6 contiguous planes -> adjacent bands (10 shared halo rows) hit the
//    same XCD L2 instead of scattering across 8 XCDs.
//  - tiles 0/1 V-loads hoisted above the w-preamble: first-load latency hides
//    under w row-sum + sync + band_f build (loads cannot sink past barrier).
__global__ __launch_bounds__(512, 2) void ssim_band(
    const float* __restrict__ in, const float* __restrict__ tgt,
    const float* __restrict__ w, float* __restrict__ partial)
{
    __shared__ __attribute__((aligned(16))) _Float16 vlds[4][16][VP];
    __shared__ float g1s[16];
    __shared__ float red[8];

    const int tid   = threadIdx.x;
    const int lane  = tid & 63;
    const int wv    = tid >> 6;          // wave id 0..7
    // XCD-chunked bijective swizzle (HW dispatches flat ids round-robin
    // across 8 XCDs; 1536 % 8 == 0 so this is a bijection).
    const int f     = blockIdx.x;
    const int s     = ((f & 7) * (NBLK / 8)) + (f >> 3);
    const int band  = s & (NBAND - 1);
    const int plane = s >> 5;
    const int r0 = band * 16;
    const bool edge = (r0 + 16 > OUT_N);          // block-uniform (band 31)
    const float* __restrict__ ip = in  + (size_t)plane * (IMG*IMG);
    const float* __restrict__ tp = tgt + (size_t)plane * (IMG*IMG);

    const int fi = lane & 15;            // A-row / B-col / D-col index
    const int kg = lane >> 4;            // k-group (0..3)
    const int kB = kg * 8;               // k base for this lane

    // Hoisted V-load indices: row r0+kB+q (clamped; k>=26 weights are zero so
    // clamped garbage contributes 0), col base wv*64 + fi.
    int idx[8];
    #pragma unroll
    for (int q = 0; q < 8; ++q) {
        const int rr = min(r0 + kB + q, IMG - 1);
        idx[q] = rr * IMG + wv * 64 + fi;
    }

#define VLOAD(T, XS, YS) \
    { _Pragma("unroll") \
      for (int q = 0; q < 8; ++q) { \
          XS[q] = ip[idx[q] + 16*(T)]; \
          YS[q] = tp[idx[q] + 16*(T)]; \
      } }

    // Early issue: tiles 0 and 1 load under the w-preamble + barrier below.
    float xA[8], yA[8], xB[8], yB[8];
    VLOAD(0, xA, yA)
    VLOAD(1, xB, yB)

    // 1D factor = row sums of the 2D kernel (exact: w2d = outer(g,g), sum = 1)
    if (tid < 11) {
        float ws_ = 0.f;
        #pragma unroll
        for (int j = 0; j < 11; ++j) ws_ += w[tid*11 + j];
        g1s[tid] = ws_;
    }
    __syncthreads();
    float g[11];
    #pragma unroll
    for (int j = 0; j < 11; ++j)
        g[j] = __int_as_float(__builtin_amdgcn_readfirstlane(__float_as_int(g1s[j])));

    // Banded weight fragment: band_f[q] = g[kB+q - fi] (zero outside 0..10).
    f16x8 band_f;
    #pragma unroll
    for (int q = 0; q < 8; ++q) {
        float wq = 0.f;
        #pragma unroll
        for (int j = 0; j <= 10; ++j)
            wq = (kB + q - fi == j) ? g[j] : wq;
        band_f[q] = (_Float16)wq;
    }

    float acc = 0.f;
    const f32x4 z = {0.f, 0.f, 0.f, 0.f};

#define VSTORE(F, D) \
    { H4u u_; \
      u_.p[0] = __builtin_amdgcn_cvt_pkrtz((D)[0], (D)[1]); \
      u_.p[1] = __builtin_amdgcn_cvt_pkrtz((D)[2], (D)[3]); \
      *reinterpret_cast<h4*>(&vlds[F][fi][cb_]) = u_.v; }

#define VPROC(T, XS, YS) \
    { H8u ux, uy; \
      ux.p[0] = __builtin_amdgcn_cvt_pkrtz(XS[0], XS[1]); \
      ux.p[1] = __builtin_amdgcn_cvt_pkrtz(XS[2], XS[3]); \
      ux.p[2] = __builtin_amdgcn_cvt_pkrtz(XS[4], XS[5]); \
      ux.p[3] = __builtin_amdgcn_cvt_pkrtz(XS[6], XS[7]); \
      uy.p[0] = __builtin_amdgcn_cvt_pkrtz(YS[0], YS[1]); \
      uy.p[1] = __builtin_amdgcn_cvt_pkrtz(YS[2], YS[3]); \
      uy.p[2] = __builtin_amdgcn_cvt_pkrtz(YS[4], YS[5]); \
      uy.p[3] = __builtin_amdgcn_cvt_pkrtz(YS[6], YS[7]); \
      f16x8 fX = ux.v, fY = uy.v; \
      f16x8 fS = fX + fY, fD = fX - fY;      /* v_pk_add/sub_f16 */ \
      f16x8 fP = fS * fS, fM = fD * fD;      /* v_pk_mul_f16 */ \
      f32x4 dX = __builtin_amdgcn_mfma_f32_16x16x32_f16(fX, band_f, z, 0, 0, 0); \
      f32x4 dY = __builtin_amdgcn_mfma_f32_16x16x32_f16(fY, band_f, z, 0, 0, 0); \
      f32x4 dP = __builtin_amdgcn_mfma_f32_16x16x32_f16(fP, band_f, z, 0, 0, 0); \
      f32x4 dM = __builtin_amdgcn_mfma_f32_16x16x32_f16(fM, band_f, z, 0, 0, 0); \
      const int cb_ = (wv*4 + (T))*16 + kg*4; \
      VSTORE(0, dX) VSTORE(1, dY) VSTORE(2, dP) VSTORE(3, dM) }

    VPROC(0, xA, yA)
    VLOAD(2, xA, yA)
    VPROC(1, xB, yB)
    VLOAD(3, xB, yB)
    VPROC(2, xA, yA)
    VPROC(3, xB, yB)

    __syncthreads();     // the only inter-phase barrier

    // ---- H phase: A-frag = vlds[f][fi][c0+kB..+7] (one b128/field) ----
#define HPROC(T) \
    { const int c0_ = (wv*4 + (T))*16; \
      const int kb_ = min(c0_ + kB, IMG - 8); \
      f16x8 aX = *reinterpret_cast<const f16x8*>(&vlds[0][fi][kb_]); \
      f16x8 aY = *reinterpret_cast<const f16x8*>(&vlds[1][fi][kb_]); \
      f16x8 aP = *reinterpret_cast<const f16x8*>(&vlds[2][fi][kb_]); \
      f16x8 aM = *reinterpret_cast<const f16x8*>(&vlds[3][fi][kb_]); \
      f32x4 dX = __builtin_amdgcn_mfma_f32_16x16x32_f16(aX, band_f, z, 0, 0, 0); \
      f32x4 dY = __builtin_amdgcn_mfma_f32_16x16x32_f16(aY, band_f, z, 0, 0, 0); \
      f32x4 dP = __builtin_amdgcn_mfma_f32_16x16x32_f16(aP, band_f, z, 0, 0, 0); \
      f32x4 dM = __builtin_amdgcn_mfma_f32_16x16x32_f16(aM, band_f, z, 0, 0, 0); \
      const int oc = c0_ + fi; \
      if (oc < OUT_N) { \
          if (!edge) { \
              v2f mx0 = {dX[0], dX[1]}, my0 = {dY[0], dY[1]}; \
              v2f P0  = {dP[0], dP[1]}, M0  = {dM[0], dM[1]}; \
              v2f mx1 = {dX[2], dX[3]}, my1 = {dY[2], dY[3]}; \
              v2f P1  = {dP[2], dP[3]}, M1  = {dM[2], dM[3]}; \
              acc += ssim_px2(mx0, my0, P0, M0); \
              acc += ssim_px2(mx1, my1, P1, M1); \
          } else { \
              _Pragma("unroll") \
              for (int m = 0; m < 4; ++m) { \
                  const int oy = r0 + kg*4 + m; \
                  if (oy < OUT_N) \
                      acc += ssim_px(dX[m], dY[m], dP[m], dM[m]); \
              } \
          } } }

    HPROC(0) HPROC(1) HPROC(2) HPROC(3)

    // block reduction: wave shuffle, then 8 wave-partials through LDS
    #pragma unroll
    for (int off = 32; off > 0; off >>= 1)
        acc += __shfl_down(acc, off, 64);
    if (lane == 0) red[wv] = acc;
    __syncthreads();
    if (tid == 0) {
        float t = 0.f;
        #pragma unroll
        for (int i = 0; i < 8; ++i) t += red[i];
        partial[s] = t;
    }
}

// Deterministic final reduction: fixed traversal, double accumulation.
__global__ __launch_bounds__(256) void ssim_final(
    const float* __restrict__ partial, int n, float* __restrict__ out)
{
    __shared__ double red[256];
    double s = 0.0;
    for (int i = threadIdx.x; i < n; i += 256) s += (double)partial[i];
    red[threadIdx.x] = s;
    __syncthreads();
    for (int off = 128; off > 0; off >>= 1) {
        if (threadIdx.x < off) red[threadIdx.x] += red[threadIdx.x + off];
        __syncthreads();
    }
    if (threadIdx.x == 0) out[0] = (float)(1.0 - red[0] / (double)NPLANE);
}

extern "C" void kernel_launch(void* const* d_in, const int* in_sizes, int n_in,
                              void* d_out, int out_size, void* d_ws, size_t ws_size,
                              hipStream_t stream) {
    const float* in  = (const float*)d_in[0];
    const float* tgt = (const float*)d_in[1];
    const float* wt  = (const float*)d_in[2];
    float* out  = (float*)d_out;
    float* part = (float*)d_ws;

    ssim_band<<<dim3(NBLK), 512, 0, stream>>>(in, tgt, wt, part);
    ssim_final<<<1, 256, 0, stream>>>(part, NBLK, out);
}